// Round 1
// baseline (3627.633 us; speedup 1.0000x reference)
//
#include <hip/hip_runtime.h>
#include <math.h>

#define NN 6000
#define NP 6144     // padded to 256*24
#define DD 64
#define KTOP 30

// acc layout (doubles):
// [0..3] self_all per mat, [4..7] self_top per mat, [8..11] self_term per mat,
// [12..13] cross_all per group, [14..17] cross_top indexed by MASK matrix id
#define ACC_ALL   0
#define ACC_TOP   4
#define ACC_SELF  8
#define ACC_XALL  12
#define ACC_XTOP  14
#define ACC_COUNT 18

__device__ __forceinline__ unsigned long long ullmax2(unsigned long long a, unsigned long long b) {
  return a > b ? a : b;
}

// order-preserving float->uint, packed with inverted index for min-index tie-break
__device__ __forceinline__ unsigned long long simkey(float v, int m) {
  unsigned int u = __float_as_uint(v);
  u = (u & 0x80000000u) ? ~u : (u | 0x80000000u);
  return ((unsigned long long)u << 32) | (unsigned long long)(0xFFFFFFFFu - (unsigned int)m);
}

__global__ void k_zero(double* __restrict__ acc) {
  int t = threadIdx.x;
  if (t < ACC_COUNT) acc[t] = 0.0;
}

__global__ __launch_bounds__(256) void k_normalize(
    const float* __restrict__ in0, const float* __restrict__ in1,
    const float* __restrict__ in2, const float* __restrict__ in3,
    float* __restrict__ nrm, double* __restrict__ acc) {
  __shared__ double sred[4];
  const int tid  = threadIdx.x;
  const int lane = tid & 63, wv = tid >> 6;
  const int row  = blockIdx.x * 4 + wv;     // 0..23999, 6000%4==0 so block is mat-uniform
  const int mat  = row / NN;
  const int r    = row - mat * NN;
  const float* src = (mat == 0) ? in0 : (mat == 1) ? in1 : (mat == 2) ? in2 : in3;
  float v = src[(size_t)r * DD + lane];
  float s = v * v;
  #pragma unroll
  for (int o = 32; o > 0; o >>= 1) s += __shfl_xor(s, o);
  float dn = fmaxf(sqrtf(s), 1e-12f);
  float a = v / dn;
  nrm[(size_t)row * DD + lane] = a;
  float st = __expf(a * a * 10.0f);   // exp((a*a)/SSL_TEMP), SSL_TEMP=0.1
  #pragma unroll
  for (int o = 32; o > 0; o >>= 1) st += __shfl_xor(st, o);
  if (lane == 0) sred[wv] = (double)st;
  __syncthreads();
  if (tid == 0) atomicAdd(&acc[ACC_SELF + mat], sred[0] + sred[1] + sred[2] + sred[3]);
}

// One block handles 2 rows of one matrix: computes full sim rows into LDS,
// accumulates sum(exp(sim)) and finds top-30 indices via cached-local-max argmax.
__global__ __launch_bounds__(256) void k_topk(
    const float* __restrict__ nrm, int* __restrict__ idxbuf, double* __restrict__ acc) {
  __shared__ float s_sim[2][NP];            // 48 KiB
  __shared__ unsigned long long s_key[4];
  __shared__ double s_dred[4];

  const int tid  = threadIdx.x;
  const int lane = tid & 63;
  const int wv   = tid >> 6;

  const int brow = blockIdx.x * 2;          // 0..23998 (mat-uniform: 6000 even)
  const int mat  = brow / NN;
  const int r0   = brow - mat * NN;
  const float* __restrict__ x = nrm + (size_t)mat * NN * DD;

  // each 16-lane group cooperatively computes one sim per iteration (per row)
  const int c16 = lane & 15;
  const float4 a0 = *(const float4*)(x + (size_t)(r0 + 0) * DD + c16 * 4);
  const float4 a1 = *(const float4*)(x + (size_t)(r0 + 1) * DD + c16 * 4);

  const int g = tid >> 4;                   // group id 0..15
  for (int it = 0; it < NP / 16; ++it) {
    int m = it * 16 + g;
    float4 xm = make_float4(0.f, 0.f, 0.f, 0.f);
    if (m < NN) xm = *(const float4*)(x + (size_t)m * DD + c16 * 4);
    float d0 = xm.x * a0.x + xm.y * a0.y + xm.z * a0.z + xm.w * a0.w;
    float d1 = xm.x * a1.x + xm.y * a1.y + xm.z * a1.z + xm.w * a1.w;
    #pragma unroll
    for (int o = 1; o < 16; o <<= 1) {
      d0 += __shfl_xor(d0, o);
      d1 += __shfl_xor(d1, o);
    }
    if (c16 == 0) {
      s_sim[0][m] = (m < NN) ? d0 : -INFINITY;
      s_sim[1][m] = (m < NN) ? d1 : -INFINITY;
    }
  }
  __syncthreads();

  // threads 0..127 -> row 0, 128..255 -> row 1 (waves {0,1} / {2,3})
  const int row  = tid >> 7;
  const int stid = tid & 127;
  float* sim = s_sim[row];

  double lsum = 0.0;                        // sum(exp) over this thread's slots
  unsigned long long lkey = 0ull;           // cached local max key
  for (int j = 0; j < NP / 128; ++j) {      // 48 slots/thread
    int m = stid + j * 128;
    float v = sim[m];
    if (m < NN) lsum += (double)__expf(v);
    lkey = ullmax2(lkey, simkey(v, m));
  }

  double ltop = 0.0;                        // only row-leader (stid==0) uses this
  for (int t = 0; t < KTOP; ++t) {
    unsigned long long k = lkey;
    #pragma unroll
    for (int o = 32; o > 0; o >>= 1) k = ullmax2(k, __shfl_xor(k, o));
    if (lane == 0) s_key[wv] = k;
    __syncthreads();
    unsigned long long wk = ullmax2(s_key[row * 2], s_key[row * 2 + 1]);
    int wm = (int)(0xFFFFFFFFu - (unsigned int)(wk & 0xFFFFFFFFull));
    unsigned int wu = (unsigned int)(wk >> 32);
    float wval = (wu & 0x80000000u) ? __uint_as_float(wu ^ 0x80000000u)
                                    : __uint_as_float(~wu);
    if (stid == 0) {
      idxbuf[((size_t)mat * NN + r0 + row) * KTOP + t] = wm;
      ltop += (double)__expf(wval);
    }
    // owning thread invalidates the winner and rebuilds its cached local max
    if (stid == (wm & 127)) {
      sim[wm] = -INFINITY;
      unsigned long long nk = 0ull;
      for (int j = 0; j < NP / 128; ++j) {
        int m = stid + j * 128;
        nk = ullmax2(nk, simkey(sim[m], m));
      }
      lkey = nk;
    }
    __syncthreads();
  }

  #pragma unroll
  for (int o = 32; o > 0; o >>= 1) lsum += __shfl_xor(lsum, o);
  if (lane == 0) s_dred[wv] = lsum;
  __syncthreads();
  if (tid == 0) atomicAdd(&acc[ACC_ALL + mat], s_dred[0] + s_dred[1] + s_dred[2] + s_dred[3]);
  if (stid == 0) atomicAdd(&acc[ACC_TOP + mat], ltop);
}

// 64x64 output tile per block, fp32 register-tiled; sums exp(a@b^T) over all entries.
__global__ __launch_bounds__(256) void k_cross_all(
    const float* __restrict__ nrm, double* __restrict__ acc) {
  __shared__ float As[DD][68];              // [k][m], pad 68 -> 16B-aligned rows, no conflicts
  __shared__ float Bs[DD][68];              // [k][n]
  __shared__ double s_dred[4];
  const int g = blockIdx.z;
  const float* __restrict__ A = nrm + (size_t)(2 * g) * NN * DD;
  const float* __restrict__ B = nrm + (size_t)(2 * g + 1) * NN * DD;
  const int m0 = blockIdx.x * 64;
  const int n0 = blockIdx.y * 64;
  const int tid = threadIdx.x;

  {
    const int ar = tid >> 2;                // 0..63 (row within tile)
    const int cbase = tid & 3;
    #pragma unroll
    for (int j = 0; j < 4; ++j) {
      int c = cbase + j * 4;                // float4 index 0..15
      float4 va = make_float4(0.f, 0.f, 0.f, 0.f), vb = make_float4(0.f, 0.f, 0.f, 0.f);
      if (m0 + ar < NN) va = *(const float4*)(A + (size_t)(m0 + ar) * DD + c * 4);
      if (n0 + ar < NN) vb = *(const float4*)(B + (size_t)(n0 + ar) * DD + c * 4);
      As[c * 4 + 0][ar] = va.x; As[c * 4 + 1][ar] = va.y;
      As[c * 4 + 2][ar] = va.z; As[c * 4 + 3][ar] = va.w;
      Bs[c * 4 + 0][ar] = vb.x; Bs[c * 4 + 1][ar] = vb.y;
      Bs[c * 4 + 2][ar] = vb.z; Bs[c * 4 + 3][ar] = vb.w;
    }
  }
  __syncthreads();

  const int ty = tid >> 4, tx = tid & 15;
  float r[4][4] = {};
  #pragma unroll
  for (int k = 0; k < DD; ++k) {
    float4 a4 = *(const float4*)&As[k][ty * 4];
    float4 b4 = *(const float4*)&Bs[k][tx * 4];
    float av[4] = {a4.x, a4.y, a4.z, a4.w};
    float bv[4] = {b4.x, b4.y, b4.z, b4.w};
    #pragma unroll
    for (int i = 0; i < 4; ++i)
      #pragma unroll
      for (int jj = 0; jj < 4; ++jj)
        r[i][jj] = fmaf(av[i], bv[jj], r[i][jj]);
  }

  double lsum = 0.0;
  #pragma unroll
  for (int i = 0; i < 4; ++i) {
    int m = m0 + ty * 4 + i;
    #pragma unroll
    for (int jj = 0; jj < 4; ++jj) {
      int n = n0 + tx * 4 + jj;
      if (m < NN && n < NN) lsum += (double)__expf(r[i][jj]);
    }
  }
  const int lane = tid & 63, wv = tid >> 6;
  #pragma unroll
  for (int o = 32; o > 0; o >>= 1) lsum += __shfl_xor(lsum, o);
  if (lane == 0) s_dred[wv] = lsum;
  __syncthreads();
  if (tid == 0) atomicAdd(&acc[ACC_XALL + g], s_dred[0] + s_dred[1] + s_dred[2] + s_dred[3]);
}

// For mask-matrix mm (partner pm = mm^1 in the same group):
// acc[ACC_XTOP+mm] = sum_n sum_{j in topk_mm(n)} exp( pm[n] . mm[j] )
__global__ __launch_bounds__(256) void k_gather(
    const float* __restrict__ nrm, const int* __restrict__ idxbuf, double* __restrict__ acc) {
  __shared__ double sred[4];
  const int mm = blockIdx.y;
  const int pm = mm ^ 1;
  const int n  = blockIdx.x;
  const int tid = threadIdx.x, lane = tid & 63, wv = tid >> 6;
  const float* __restrict__ Bm = nrm + (size_t)mm * NN * DD;
  const float* __restrict__ Pm = nrm + (size_t)pm * NN * DD;
  const float pv = Pm[(size_t)n * DD + lane];
  const int* idx = idxbuf + ((size_t)mm * NN + n) * KTOP;
  double lsum = 0.0;
  for (int t = wv; t < KTOP; t += 4) {
    int j = idx[t];
    float prod = pv * Bm[(size_t)j * DD + lane];
    #pragma unroll
    for (int o = 32; o > 0; o >>= 1) prod += __shfl_xor(prod, o);
    if (lane == 0) lsum += (double)__expf(prod);
  }
  if (lane == 0) sred[wv] = lsum;
  __syncthreads();
  if (tid == 0) atomicAdd(&acc[ACC_XTOP + mm], sred[0] + sred[1] + sred[2] + sred[3]);
}

__global__ void k_finalize(const double* __restrict__ acc, float* __restrict__ out) {
  if (threadIdx.x != 0 || blockIdx.x != 0) return;
  const double C = (double)NN * (double)NN - (double)NN * (double)KTOP; // non-topk exp(0)=1 count
  double total = 0.0;
  for (int g = 0; g < 2; ++g) {
    int a = 2 * g, b = 2 * g + 1;
    // pair (a, b): masks mask_a (self) and mask_b (cross)
    double t1 = acc[ACC_ALL + a] - acc[ACC_TOP + a] - C + acc[ACC_SELF + a];
    double t2 = acc[ACC_XALL + g] - acc[ACC_XTOP + b] - C;
    total += -(double)NN * log(1.0 + t1 + t2);
    // pair (b, a)
    t1 = acc[ACC_ALL + b] - acc[ACC_TOP + b] - C + acc[ACC_SELF + b];
    t2 = acc[ACC_XALL + g] - acc[ACC_XTOP + a] - C;
    total += -(double)NN * log(1.0 + t1 + t2);
  }
  out[0] = (float)(total * 0.25);
}

extern "C" void kernel_launch(void* const* d_in, const int* in_sizes, int n_in,
                              void* d_out, int out_size, void* d_ws, size_t ws_size,
                              hipStream_t stream) {
  (void)in_sizes; (void)n_in; (void)out_size; (void)ws_size;
  const float* u1 = (const float*)d_in[0];
  const float* u2 = (const float*)d_in[1];
  const float* i1 = (const float*)d_in[2];
  const float* i2 = (const float*)d_in[3];
  char* ws = (char*)d_ws;
  // ws layout: norm (4*6000*64 f32 = 6.144 MB) | idx (4*6000*30 i32 = 2.88 MB) | acc (18 f64)
  float* nrm = (float*)ws;
  int* idxbuf = (int*)(ws + (size_t)4 * NN * DD * 4);
  double* acc = (double*)(ws + (size_t)4 * NN * DD * 4 + (size_t)4 * NN * KTOP * 4);
  float* out = (float*)d_out;

  hipLaunchKernelGGL(k_zero,      dim3(1),            dim3(64),  0, stream, acc);
  hipLaunchKernelGGL(k_normalize, dim3(4 * NN / 4),   dim3(256), 0, stream, u1, u2, i1, i2, nrm, acc);
  hipLaunchKernelGGL(k_topk,      dim3(4 * NN / 2),   dim3(256), 0, stream, nrm, idxbuf, acc);
  hipLaunchKernelGGL(k_cross_all, dim3(94, 94, 2),    dim3(256), 0, stream, nrm, acc);
  hipLaunchKernelGGL(k_gather,    dim3(NN, 4),        dim3(256), 0, stream, nrm, idxbuf, acc);
  hipLaunchKernelGGL(k_finalize,  dim3(1),            dim3(1),   0, stream, acc, out);
}